// Round 14
// baseline (50.485 us; speedup 1.0000x reference)
//
#include <hip/hip_runtime.h>

// CLF_K_QP_Net — bf16 MFMA, R14. B=65536, N=16, H=128, NC=2.
// Occupancy ledger refined: 2x 8-wave blocks co-reside at VGPR 64 (R9: 42%)
// but NOT at 124 (R12: 20%) -> co-residency cliff is between, ~<=112 after HW
// granularity. 1024-thr blocks always mis-allocate (VGPR 64 + spills; R10/R13)
// — abandoned. R14 = R12 with the w-pass and c-step FUSED (c[t] is pointwise
// in t) -> wacc[8] (32 VGPRs) eliminated -> est. ~96 live -> 2 blocks/CU.

typedef __attribute__((ext_vector_type(8))) short bf8_t;   // MFMA A/B frag
typedef __attribute__((ext_vector_type(4))) float f4_t;    // MFMA C/D frag

#define MFMA16(a, b, c) __builtin_amdgcn_mfma_f32_16x16x32_bf16((a), (b), (c), 0, 0, 0)

__device__ __forceinline__ float fast_tanh(float v) {
    float e = __builtin_amdgcn_exp2f(v * 2.885390081777927f);   // e^{2v}
    return 1.0f - 2.0f * __builtin_amdgcn_rcpf(e + 1.0f);       // inf-safe
}
__device__ __forceinline__ unsigned short bf16_of(float f) {
    union { float f; unsigned u; } v; v.f = f;
    return (unsigned short)((v.u + 0x8000u) >> 16);
}
__device__ __forceinline__ unsigned pk2(float a, float b) {
    union { float f; unsigned u; } va, vb; va.f = a; vb.f = b;
    return ((va.u + 0x8000u) >> 16) | ((vb.u + 0x8000u) & 0xFFFF0000u);
}
__device__ __forceinline__ float unbf(unsigned s) {           // low 16 bits
    union { unsigned u; float f; } v; v.u = s << 16; return v.f;
}
__device__ __forceinline__ float unbf_hi(unsigned s) {        // high 16 bits
    union { unsigned u; float f; } v; v.u = s & 0xFFFF0000u; return v.f;
}

// ws layout (bf16 element offsets):
// V1[128][16]:0  V1T[16][128]:2048  V2[128][128]:4096  V2T[128][128]:20480
// K1a[128][16]:36864  K2a[128][16]:38912  K1b[16][128]:40960  K2b[16][128]:43008
// A_dyn[16][16]:45056
__global__ void prep_weights(const float* __restrict__ V1_w,
                             const float* __restrict__ V2_w,
                             const float* __restrict__ K1a_w,
                             const float* __restrict__ K1b_w,
                             const float* __restrict__ K2a_w,
                             const float* __restrict__ K2b_w,
                             const float* __restrict__ A_dyn,
                             unsigned short* __restrict__ ws) {
    int i = blockIdx.x * 256 + threadIdx.x;
    if (i < 2048) {
        ws[i] = bf16_of(V1_w[i]);
        int k = i & 127;
        ws[2048 + i] = bf16_of(V1_w[k * 16 + (i >> 7)]);   // V1T[n][k]
        ws[36864 + i] = bf16_of(K1a_w[i]);
        ws[38912 + i] = bf16_of(K2a_w[i]);
        ws[40960 + i] = bf16_of(K1b_w[i]);
        ws[43008 + i] = bf16_of(K2b_w[i]);
    }
    if (i < 16384) {
        ws[4096 + i] = bf16_of(V2_w[i]);
        int k = i >> 7, h = i & 127;
        ws[20480 + i] = bf16_of(V2_w[h * 128 + k]);        // V2T[k][h]
    }
    if (i < 256) ws[45056 + i] = bf16_of(A_dyn[i]);
}

__device__ __forceinline__ bf8_t pack8(f4_t a, f4_t b) {
    union { bf8_t v; unsigned u[4]; } r;
    r.u[0] = pk2(a[0], a[1]); r.u[1] = pk2(a[2], a[3]);
    r.u[2] = pk2(b[0], b[1]); r.u[3] = pk2(b[2], b[3]);
    return r.v;
}

// LDS (shorts, STATIC): V2s[16384] | 8 waves x act[2048]  = 64 KB
__global__ void __launch_bounds__(512) clf_mfma_kernel(
    const float* __restrict__ x,
    const float* __restrict__ V1_b, const float* __restrict__ V2_b,
    const float* __restrict__ K1a_b, const float* __restrict__ K1b_b,
    const float* __restrict__ K2a_b, const float* __restrict__ K2b_b,
    const float* __restrict__ B_dyn, const float* __restrict__ x_goal,
    const float* __restrict__ u_eq,
    const unsigned short* __restrict__ ws, float* __restrict__ out, int B) {
    __shared__ unsigned short sm[32768];
    unsigned short* V2s = sm;
    const int lane = threadIdx.x & 63;
    const int wv = threadIdx.x >> 6;       // 0..7
    const int lr = lane & 15;              // batch column
    const int g = lane >> 4;               // k-group / row-group
    const int bb = (blockIdx.x * 8 + wv) * 16 + lr;
    unsigned short* buf = sm + 16384 + wv * 2048;   // single 4KB act buffer

    if (blockIdx.x == 0 && threadIdx.x == 0) out[2 * B] = 0.0f;  // relaxation

    // ---- stage V2 into LDS with row-swizzle ----
#pragma unroll
    for (int q = 0; q < 4; ++q) {
        int e = (q * 512 + threadIdx.x) * 8;          // 8-elem chunk
        int r = e >> 7;
        int d = e ^ ((r & 7) << 3);
        *reinterpret_cast<uint4*>(&V2s[d]) = *reinterpret_cast<const uint4*>(ws + 4096 + e);
    }
    __syncthreads();

    const unsigned short* wsV1 = ws;
    const unsigned short* wsV1T = ws + 2048;
    const unsigned short* wsV2T = ws + 20480;
    const unsigned short* wsK1a = ws + 36864;
    const unsigned short* wsK2a = ws + 38912;
    const unsigned short* wsK1b = ws + 40960;
    const unsigned short* wsK2b = ws + 43008;
    const unsigned short* wsA = ws + 45056;

    const int swz = (lr & 7) << 3;
    auto stA = [&](int h0, unsigned lo, unsigned hi) {
        int idx = (lr * 128 + h0) ^ swz;
        uint2 v; v.x = lo; v.y = hi;
        *reinterpret_cast<uint2*>(buf + idx) = v;
    };
    auto ld8 = [&](int h0) -> bf8_t {
        int idx = (lr * 128 + h0) ^ swz;
        return *reinterpret_cast<const bf8_t*>(buf + idx);
    };
    auto ldW = [&](const unsigned short* Wt, int t, int c) -> bf8_t {
        int idx = ((t * 16 + lr) * 128 + c * 32 + g * 8) ^ swz;
        return *reinterpret_cast<const bf8_t*>(Wt + idx);
    };

    // ---- x fragment (B operand for K=16 GEMMs, zero-padded to 32) ----
    bf8_t xf = {0, 0, 0, 0, 0, 0, 0, 0};
    if (g < 2) {
        const float* xp = x + bb * 16 + g * 8;
        f4_t a = *reinterpret_cast<const f4_t*>(xp);
        f4_t b = *reinterpret_cast<const f4_t*>(xp + 4);
        xf = pack8(a, b);
    }

    // ---- first-layer tanh net -> act buf (optionally keep D-frag pairs) ----
    auto actnet = [&](const unsigned short* wsW, const float* bias, unsigned* keep) {
#pragma unroll
        for (int t = 0; t < 8; ++t) {
            bf8_t af = {0, 0, 0, 0, 0, 0, 0, 0};
            if (g < 2) af = *reinterpret_cast<const bf8_t*>(wsW + (t * 16 + lr) * 16 + g * 8);
            f4_t acc = {0.f, 0.f, 0.f, 0.f};
            acc = MFMA16(af, xf, acc);
            f4_t bs = *reinterpret_cast<const f4_t*>(bias + t * 16 + g * 4);
            float v0 = fast_tanh(acc[0] + bs[0]);
            float v1 = fast_tanh(acc[1] + bs[1]);
            float v2 = fast_tanh(acc[2] + bs[2]);
            float v3 = fast_tanh(acc[3] + bs[3]);
            unsigned lo = pk2(v0, v1), hi = pk2(v2, v3);
            if (keep) { keep[2 * t] = lo; keep[2 * t + 1] = hi; }
            stA(t * 16 + g * 4, lo, hi);
        }
    };
    auto ldfrag = [&](bf8_t (&f)[4]) {
        f[0] = ld8(0 + g * 8); f[1] = ld8(32 + g * 8);
        f[2] = ld8(64 + g * 8); f[3] = ld8(96 + g * 8);
    };
    // second layer over a ws A-operand (K1b/K2b/V1T rows), split acc chain
    auto kmul = [&](const unsigned short* wsKb, const bf8_t (&f)[4]) -> f4_t {
        const unsigned short* ar = wsKb + lr * 128 + g * 8;
        f4_t za = {0.f, 0.f, 0.f, 0.f}, zb = {0.f, 0.f, 0.f, 0.f};
        za = MFMA16(*reinterpret_cast<const bf8_t*>(ar), f[0], za);
        zb = MFMA16(*reinterpret_cast<const bf8_t*>(ar + 32), f[1], zb);
        za = MFMA16(*reinterpret_cast<const bf8_t*>(ar + 64), f[2], za);
        zb = MFMA16(*reinterpret_cast<const bf8_t*>(ar + 96), f[3], zb);
        f4_t k;
        k[0] = za[0] + zb[0]; k[1] = za[1] + zb[1];
        k[2] = za[2] + zb[2]; k[3] = za[3] + zb[3];
        return k;
    };

    // ---- K1 net (through act buf) ----
    actnet(wsK1a, K1a_b, nullptr);
    bf8_t frag[4];
    ldfrag(frag);
    f4_t k1 = kmul(wsK1b, frag);
    // ---- K2 net ----
    actnet(wsK2a, K2a_b, nullptr);
    ldfrag(frag);
    f4_t k2 = kmul(wsK2b, frag);

    // ---- t1 net: buf + reg copy (for the c-step) ----
    unsigned T1[16];
    actnet(wsV1, V1_b, T1);
    bf8_t t1f[4];
    ldfrag(t1f);

    // ---- t2 pass: Z2^T = V2 . t1^T; V partials; s2 -> buf ----
    float vsum = 0.f;
#pragma unroll
    for (int t = 0; t < 8; ++t) {
        f4_t za = {0.f, 0.f, 0.f, 0.f}, zb = {0.f, 0.f, 0.f, 0.f};
        za = MFMA16(ldW(V2s, t, 0), t1f[0], za);
        zb = MFMA16(ldW(V2s, t, 1), t1f[1], zb);
        za = MFMA16(ldW(V2s, t, 2), t1f[2], za);
        zb = MFMA16(ldW(V2s, t, 3), t1f[3], zb);
        f4_t bs = *reinterpret_cast<const f4_t*>(V2_b + t * 16 + g * 4);
        float s0, s1, s2v, s3;
        {
            float t2;
            t2 = fast_tanh(za[0] + zb[0] + bs[0]); vsum = fmaf(t2, t2, vsum); s0 = t2 * (1.f - t2 * t2);
            t2 = fast_tanh(za[1] + zb[1] + bs[1]); vsum = fmaf(t2, t2, vsum); s1 = t2 * (1.f - t2 * t2);
            t2 = fast_tanh(za[2] + zb[2] + bs[2]); vsum = fmaf(t2, t2, vsum); s2v = t2 * (1.f - t2 * t2);
            t2 = fast_tanh(za[3] + zb[3] + bs[3]); vsum = fmaf(t2, t2, vsum); s3 = t2 * (1.f - t2 * t2);
        }
        stA(t * 16 + g * 4, pk2(s0, s1), pk2(s2v, s3));
    }
    bf8_t s2f[4];
    ldfrag(s2f);

    // ---- FUSED w+c pass: per t, wacc_t = V2T_t . s2f, then c_t -> buf ----
    // (c[t] depends only on wacc[t] and T1[t] -> no wacc[8] array; -32 VGPRs)
#pragma unroll
    for (int t = 0; t < 8; ++t) {
        const unsigned short* ar = wsV2T + (t * 16 + lr) * 128 + g * 8;
        f4_t za = {0.f, 0.f, 0.f, 0.f}, zb = {0.f, 0.f, 0.f, 0.f};
        za = MFMA16(*reinterpret_cast<const bf8_t*>(ar), s2f[0], za);
        zb = MFMA16(*reinterpret_cast<const bf8_t*>(ar + 32), s2f[1], zb);
        za = MFMA16(*reinterpret_cast<const bf8_t*>(ar + 64), s2f[2], za);
        zb = MFMA16(*reinterpret_cast<const bf8_t*>(ar + 96), s2f[3], zb);
        float t0v = unbf(T1[2 * t]), t1v = unbf_hi(T1[2 * t]);
        float t2v = unbf(T1[2 * t + 1]), t3v = unbf_hi(T1[2 * t + 1]);
        float c0 = (za[0] + zb[0]) * (1.f - t0v * t0v);
        float c1 = (za[1] + zb[1]) * (1.f - t1v * t1v);
        float c2 = (za[2] + zb[2]) * (1.f - t2v * t2v);
        float c3 = (za[3] + zb[3]) * (1.f - t3v * t3v);
        stA(t * 16 + g * 4, pk2(c0, c1), pk2(c2, c3));
    }
    bf8_t cf[4];
    ldfrag(cf);

    // ---- gV^T = V1^T . c^T ----
    f4_t gacc = kmul(wsV1T, cf);

    // ---- f^T = A_dyn . x^T ----
    bf8_t afA = {0, 0, 0, 0, 0, 0, 0, 0};
    if (g < 2) afA = *reinterpret_cast<const bf8_t*>(wsA + lr * 16 + g * 8);
    f4_t fz = {0.f, 0.f, 0.f, 0.f};
    f4_t fac = MFMA16(afA, xf, fz);

    // ---- epilogue ----
    f4_t xv = *reinterpret_cast<const f4_t*>(x + bb * 16 + g * 4);
    f4_t xg = *reinterpret_cast<const f4_t*>(x_goal + g * 4);
    f4_t k1b = *reinterpret_cast<const f4_t*>(K1b_b + g * 4);
    f4_t k2b = *reinterpret_cast<const f4_t*>(K2b_b + g * 4);
    f4_t bd0 = *reinterpret_cast<const f4_t*>(B_dyn + g * 8);
    f4_t bd1 = *reinterpret_cast<const f4_t*>(B_dyn + g * 8 + 4);
    float up0 = 0.f, up1 = 0.f, Lf = 0.f;
#pragma unroll
    for (int r = 0; r < 4; ++r) {
        float dx = xv[r] - xg[r];
        up0 = fmaf(k1[r] + k1b[r], dx, up0);
        up1 = fmaf(k2[r] + k2b[r], dx, up1);
        Lf = fmaf(gacc[r], fac[r], Lf);
    }
    float Lg0 = gacc[0] * bd0[0] + gacc[1] * bd0[2] + gacc[2] * bd1[0] + gacc[3] * bd1[2];
    float Lg1 = gacc[0] * bd0[1] + gacc[1] * bd0[3] + gacc[2] * bd1[1] + gacc[3] * bd1[3];
    up0 += __shfl_xor(up0, 16); up0 += __shfl_xor(up0, 32);
    up1 += __shfl_xor(up1, 16); up1 += __shfl_xor(up1, 32);
    Lf += __shfl_xor(Lf, 16); Lf += __shfl_xor(Lf, 32);
    Lg0 += __shfl_xor(Lg0, 16); Lg0 += __shfl_xor(Lg0, 32);
    Lg1 += __shfl_xor(Lg1, 16); Lg1 += __shfl_xor(Lg1, 32);
    vsum += __shfl_xor(vsum, 16); vsum += __shfl_xor(vsum, 32);

    float u0 = u_eq[0] - up0;
    float u1 = u_eq[1] - up1;
    float V = 0.5f * vsum;
    float G = fmaf(Lg0, u0, fmaf(Lg1, u1, V));
    float Vd = 0.5f * (fmaxf(Lf + G, 0.f) + fmaxf(fmaf(1.2f, Lf, G), 0.f));

    if (g == 0) {
        float2 uo; uo.x = u0; uo.y = u1;
        *reinterpret_cast<float2*>(out + 2 * bb) = uo;
    } else if (g == 1) {
        out[2 * B + 1 + bb] = V;
    } else if (g == 2) {
        out[3 * B + 1 + bb] = Vd;
    }
}

extern "C" void kernel_launch(void* const* d_in, const int* in_sizes, int n_in,
                              void* d_out, int out_size, void* d_ws, size_t ws_size,
                              hipStream_t stream) {
    const float* x = (const float*)d_in[0];
    const float* V1_w = (const float*)d_in[1];
    const float* V1_b = (const float*)d_in[2];
    const float* V2_w = (const float*)d_in[3];
    const float* V2_b = (const float*)d_in[4];
    const float* K1a_w = (const float*)d_in[5];
    const float* K1a_b = (const float*)d_in[6];
    const float* K1b_w = (const float*)d_in[7];
    const float* K1b_b = (const float*)d_in[8];
    const float* K2a_w = (const float*)d_in[9];
    const float* K2a_b = (const float*)d_in[10];
    const float* K2b_w = (const float*)d_in[11];
    const float* K2b_b = (const float*)d_in[12];
    const float* A_dyn = (const float*)d_in[13];
    const float* B_dyn = (const float*)d_in[14];
    const float* x_goal = (const float*)d_in[15];
    const float* u_eq = (const float*)d_in[16];
    float* out = (float*)d_out;
    unsigned short* ws = (unsigned short*)d_ws;

    const int B = in_sizes[0] / 16;   // 65536
    prep_weights<<<64, 256, 0, stream>>>(V1_w, V2_w, K1a_w, K1b_w, K2a_w, K2b_w, A_dyn, ws);
    clf_mfma_kernel<<<512, 512, 0, stream>>>(
        x, V1_b, V2_b, K1a_b, K1b_b, K2a_b, K2b_b,
        B_dyn, x_goal, u_eq, ws, out, B);
}

// Round 15
// 38.060 us; speedup vs baseline: 1.3265x; 1.3265x over previous
//
#include <hip/hip_runtime.h>

// CLF_K_QP_Net — bf16 MFMA, R15. B=65536, N=16, H=128, NC=2.
// Ledger: co-residency (2 blocks/CU) unreachable — VGPR 104 clean still 20%
// occ (R14), cliff is <=~64 which this body can't hit (R9: 64+spills). R8
// (39.6us) remains champion: 2 act buffers (K1/K2 chains independent),
// V2s+V2Ts staged. R15 = R8 +:
//  (1) V1T/K1b/K2b also staged in LDS (swizzled) — second-layer kmul reads
//      leave the L1/L2 latency chain; L1 now holds only V1/K1a/K2a/biases.
//  (2) w-pass and c-step fused (R14-verified): wacc[8] (32 VGPR) eliminated.
//  LDS = 32K(V2s)+32K(V2Ts)+6K(V1T,K1b,K2b)+64K(8 waves x bufA,bufB) = 134KB.
//  1 block/CU accepted; attack is chain latency, not occupancy.

typedef __attribute__((ext_vector_type(8))) short bf8_t;   // MFMA A/B frag
typedef __attribute__((ext_vector_type(4))) float f4_t;    // MFMA C/D frag
typedef __attribute__((ext_vector_type(4))) short s4_t;

#define MFMA16(a, b, c) __builtin_amdgcn_mfma_f32_16x16x32_bf16((a), (b), (c), 0, 0, 0)

__device__ __forceinline__ float fast_tanh(float v) {
    float e = __builtin_amdgcn_exp2f(v * 2.885390081777927f);   // e^{2v}
    return 1.0f - 2.0f * __builtin_amdgcn_rcpf(e + 1.0f);       // inf-safe
}
__device__ __forceinline__ unsigned short bf16_of(float f) {
    union { float f; unsigned u; } v; v.f = f;
    return (unsigned short)((v.u + 0x8000u) >> 16);
}
__device__ __forceinline__ unsigned pk2(float a, float b) {
    union { float f; unsigned u; } va, vb; va.f = a; vb.f = b;
    return ((va.u + 0x8000u) >> 16) | ((vb.u + 0x8000u) & 0xFFFF0000u);
}
__device__ __forceinline__ float unbf(unsigned short s) {
    union { unsigned u; float f; } v; v.u = ((unsigned)s) << 16; return v.f;
}

// ws layout (bf16 element offsets):
// V1[128][16]:0  V1T[16][128]:2048  V2[128][128]:4096  V2T[128][128]:20480
// K1a[128][16]:36864  K2a[128][16]:38912  K1b[16][128]:40960  K2b[16][128]:43008
// A_dyn[16][16]:45056
__global__ void prep_weights(const float* __restrict__ V1_w,
                             const float* __restrict__ V2_w,
                             const float* __restrict__ K1a_w,
                             const float* __restrict__ K1b_w,
                             const float* __restrict__ K2a_w,
                             const float* __restrict__ K2b_w,
                             const float* __restrict__ A_dyn,
                             unsigned short* __restrict__ ws) {
    int i = blockIdx.x * 256 + threadIdx.x;
    if (i < 2048) {
        ws[i] = bf16_of(V1_w[i]);
        int k = i & 127;
        ws[2048 + i] = bf16_of(V1_w[k * 16 + (i >> 7)]);   // V1T[n][k]
        ws[36864 + i] = bf16_of(K1a_w[i]);
        ws[38912 + i] = bf16_of(K2a_w[i]);
        ws[40960 + i] = bf16_of(K1b_w[i]);
        ws[43008 + i] = bf16_of(K2b_w[i]);
    }
    if (i < 16384) {
        ws[4096 + i] = bf16_of(V2_w[i]);
        int k = i >> 7, h = i & 127;
        ws[20480 + i] = bf16_of(V2_w[h * 128 + k]);        // V2T[k][h]
    }
    if (i < 256) ws[45056 + i] = bf16_of(A_dyn[i]);
}

__device__ __forceinline__ bf8_t pack8(f4_t a, f4_t b) {
    union { bf8_t v; unsigned u[4]; } r;
    r.u[0] = pk2(a[0], a[1]); r.u[1] = pk2(a[2], a[3]);
    r.u[2] = pk2(b[0], b[1]); r.u[3] = pk2(b[2], b[3]);
    return r.v;
}

// LDS (shorts, dynamic): V2s[16384] | V2Ts[16384] | V1Ts[2048] | K1bs[2048]
//                        | K2bs[2048] | 8 waves x {bufA 2048, bufB 2048}
// total 71680 shorts = 143360 B (incl. 8 waves act) -> 1 block/CU.
__global__ void __launch_bounds__(512) clf_mfma_kernel(
    const float* __restrict__ x,
    const float* __restrict__ V1_b, const float* __restrict__ V2_b,
    const float* __restrict__ K1a_b, const float* __restrict__ K1b_b,
    const float* __restrict__ K2a_b, const float* __restrict__ K2b_b,
    const float* __restrict__ B_dyn, const float* __restrict__ x_goal,
    const float* __restrict__ u_eq,
    const unsigned short* __restrict__ ws, float* __restrict__ out, int B) {
    extern __shared__ unsigned short sm[];
    unsigned short* V2s  = sm;
    unsigned short* V2Ts = sm + 16384;
    unsigned short* V1Ts = sm + 32768;
    unsigned short* K1bs = sm + 34816;
    unsigned short* K2bs = sm + 36864;
    const int lane = threadIdx.x & 63;
    const int wv = threadIdx.x >> 6;       // 0..7
    const int lr = lane & 15;              // batch column
    const int g = lane >> 4;               // k-group / row-group
    const int bb = (blockIdx.x * 8 + wv) * 16 + lr;
    unsigned short* bufA = sm + 38912 + wv * 4096;
    unsigned short* bufB = bufA + 2048;

    if (blockIdx.x == 0 && threadIdx.x == 0) out[2 * B] = 0.0f;  // relaxation

    // ---- stage V2, V2T (row-swizzled) ----
#pragma unroll
    for (int q = 0; q < 4; ++q) {
        int e = (q * 512 + threadIdx.x) * 8;          // 8-elem chunk
        int r = e >> 7;
        int d = e ^ ((r & 7) << 3);
        *reinterpret_cast<uint4*>(&V2s[d])  = *reinterpret_cast<const uint4*>(ws + 4096 + e);
        *reinterpret_cast<uint4*>(&V2Ts[d]) = *reinterpret_cast<const uint4*>(ws + 20480 + e);
    }
    // ---- stage V1T, K1b, K2b (row-swizzled, rows of 128) ----
    {
        int t3 = threadIdx.x;
        if (t3 < 256) {
            int e = t3 * 8; int r = e >> 7; int d = e ^ ((r & 7) << 3);
            *reinterpret_cast<uint4*>(&V1Ts[d]) = *reinterpret_cast<const uint4*>(ws + 2048 + e);
            *reinterpret_cast<uint4*>(&K2bs[d]) = *reinterpret_cast<const uint4*>(ws + 43008 + e);
        } else {
            int e = (t3 - 256) * 8; int r = e >> 7; int d = e ^ ((r & 7) << 3);
            *reinterpret_cast<uint4*>(&K1bs[d]) = *reinterpret_cast<const uint4*>(ws + 40960 + e);
        }
    }
    __syncthreads();

    const unsigned short* wsV1 = ws;
    const unsigned short* wsK1a = ws + 36864;
    const unsigned short* wsK2a = ws + 38912;
    const unsigned short* wsA = ws + 45056;

    const int swz = (lr & 7) << 3;
    auto stA = [&](unsigned short* buf, int h0, unsigned lo, unsigned hi) {
        int idx = (lr * 128 + h0) ^ swz;
        uint2 v; v.x = lo; v.y = hi;
        *reinterpret_cast<uint2*>(buf + idx) = v;
    };
    auto ld8 = [&](const unsigned short* buf, int h0) -> bf8_t {
        int idx = (lr * 128 + h0) ^ swz;
        return *reinterpret_cast<const bf8_t*>(buf + idx);
    };
    auto ld4 = [&](const unsigned short* buf, int h0) -> s4_t {
        int idx = (lr * 128 + h0) ^ swz;
        return *reinterpret_cast<const s4_t*>(buf + idx);
    };
    // fragment read from a row-swizzled [*][128] LDS array, row = t*16+lr
    auto ldW = [&](const unsigned short* Wt, int t, int c) -> bf8_t {
        int idx = ((t * 16 + lr) * 128 + c * 32 + g * 8) ^ swz;
        return *reinterpret_cast<const bf8_t*>(Wt + idx);
    };
    // fragment read from a row-swizzled [16][128] LDS array, row = lr
    auto ldK = [&](const unsigned short* Wt, int c) -> bf8_t {
        int idx = (lr * 128 + c * 32 + g * 8) ^ swz;
        return *reinterpret_cast<const bf8_t*>(Wt + idx);
    };

    // ---- x fragment (B operand for K=16 GEMMs, zero-padded to 32) ----
    bf8_t xf = {0, 0, 0, 0, 0, 0, 0, 0};
    if (g < 2) {
        const float* xp = x + bb * 16 + g * 8;
        f4_t a = *reinterpret_cast<const f4_t*>(xp);
        f4_t b = *reinterpret_cast<const f4_t*>(xp + 4);
        xf = pack8(a, b);
    }

    // ---- first-layer tanh net -> act buf ----
    auto actnet = [&](const unsigned short* wsW, const float* bias, unsigned short* dst) {
#pragma unroll
        for (int t = 0; t < 8; ++t) {
            bf8_t af = {0, 0, 0, 0, 0, 0, 0, 0};
            if (g < 2) af = *reinterpret_cast<const bf8_t*>(wsW + (t * 16 + lr) * 16 + g * 8);
            f4_t acc = {0.f, 0.f, 0.f, 0.f};
            acc = MFMA16(af, xf, acc);
            f4_t bs = *reinterpret_cast<const f4_t*>(bias + t * 16 + g * 4);
            float v0 = fast_tanh(acc[0] + bs[0]);
            float v1 = fast_tanh(acc[1] + bs[1]);
            float v2 = fast_tanh(acc[2] + bs[2]);
            float v3 = fast_tanh(acc[3] + bs[3]);
            stA(dst, t * 16 + g * 4, pk2(v0, v1), pk2(v2, v3));
        }
    };
    auto ldfrag = [&](const unsigned short* buf, bf8_t (&f)[4]) {
        f[0] = ld8(buf, 0 + g * 8); f[1] = ld8(buf, 32 + g * 8);
        f[2] = ld8(buf, 64 + g * 8); f[3] = ld8(buf, 96 + g * 8);
    };
    // second layer over an LDS-staged [16][128] A operand, split acc chain
    auto kmul = [&](const unsigned short* Wt, const bf8_t (&f)[4]) -> f4_t {
        f4_t za = {0.f, 0.f, 0.f, 0.f}, zb = {0.f, 0.f, 0.f, 0.f};
        za = MFMA16(ldK(Wt, 0), f[0], za);
        zb = MFMA16(ldK(Wt, 1), f[1], zb);
        za = MFMA16(ldK(Wt, 2), f[2], za);
        zb = MFMA16(ldK(Wt, 3), f[3], zb);
        f4_t k;
        k[0] = za[0] + zb[0]; k[1] = za[1] + zb[1];
        k[2] = za[2] + zb[2]; k[3] = za[3] + zb[3];
        return k;
    };

    // ---- K nets: independent DS chains through bufA / bufB ----
    actnet(wsK1a, K1a_b, bufA);
    actnet(wsK2a, K2a_b, bufB);
    bf8_t fragA[4], fragB[4];
    ldfrag(bufA, fragA);
    ldfrag(bufB, fragB);
    f4_t k1 = kmul(K1bs, fragA);
    f4_t k2 = kmul(K2bs, fragB);

    // ---- t1 -> bufA (free after k1) ----
    actnet(wsV1, V1_b, bufA);
    bf8_t t1f[4];
    ldfrag(bufA, t1f);

    // ---- t2 pass: Z2^T = V2 . t1^T; V partials; s2 -> bufB ----
    float vsum = 0.f;
#pragma unroll
    for (int t = 0; t < 8; ++t) {
        f4_t za = {0.f, 0.f, 0.f, 0.f}, zb = {0.f, 0.f, 0.f, 0.f};
        za = MFMA16(ldW(V2s, t, 0), t1f[0], za);
        zb = MFMA16(ldW(V2s, t, 1), t1f[1], zb);
        za = MFMA16(ldW(V2s, t, 2), t1f[2], za);
        zb = MFMA16(ldW(V2s, t, 3), t1f[3], zb);
        f4_t bs = *reinterpret_cast<const f4_t*>(V2_b + t * 16 + g * 4);
        float s0, s1, s2v, s3;
        {
            float t2;
            t2 = fast_tanh(za[0] + zb[0] + bs[0]); vsum = fmaf(t2, t2, vsum); s0 = t2 * (1.f - t2 * t2);
            t2 = fast_tanh(za[1] + zb[1] + bs[1]); vsum = fmaf(t2, t2, vsum); s1 = t2 * (1.f - t2 * t2);
            t2 = fast_tanh(za[2] + zb[2] + bs[2]); vsum = fmaf(t2, t2, vsum); s2v = t2 * (1.f - t2 * t2);
            t2 = fast_tanh(za[3] + zb[3] + bs[3]); vsum = fmaf(t2, t2, vsum); s3 = t2 * (1.f - t2 * t2);
        }
        stA(bufB, t * 16 + g * 4, pk2(s0, s1), pk2(s2v, s3));
    }
    bf8_t s2f[4];
    ldfrag(bufB, s2f);

    // ---- FUSED w+c pass: wacc_t = V2T_t . s2f; c_t = wacc_t*(1-t1_t^2) -> bufB
    // (t1 still intact in bufA; s2f already in regs so bufB overwrite is safe)
#pragma unroll
    for (int t = 0; t < 8; ++t) {
        f4_t za = {0.f, 0.f, 0.f, 0.f}, zb = {0.f, 0.f, 0.f, 0.f};
        za = MFMA16(ldW(V2Ts, t, 0), s2f[0], za);
        zb = MFMA16(ldW(V2Ts, t, 1), s2f[1], zb);
        za = MFMA16(ldW(V2Ts, t, 2), s2f[2], za);
        zb = MFMA16(ldW(V2Ts, t, 3), s2f[3], zb);
        s4_t tv = ld4(bufA, t * 16 + g * 4);
        float t0v = unbf((unsigned short)tv[0]);
        float t1v = unbf((unsigned short)tv[1]);
        float t2v = unbf((unsigned short)tv[2]);
        float t3v = unbf((unsigned short)tv[3]);
        float c0 = (za[0] + zb[0]) * (1.f - t0v * t0v);
        float c1 = (za[1] + zb[1]) * (1.f - t1v * t1v);
        float c2 = (za[2] + zb[2]) * (1.f - t2v * t2v);
        float c3 = (za[3] + zb[3]) * (1.f - t3v * t3v);
        stA(bufB, t * 16 + g * 4, pk2(c0, c1), pk2(c2, c3));
    }
    bf8_t cf[4];
    ldfrag(bufB, cf);

    // ---- gV^T = V1^T . c^T (V1T from LDS) ----
    f4_t gacc = kmul(V1Ts, cf);

    // ---- f^T = A_dyn . x^T ----
    bf8_t afA = {0, 0, 0, 0, 0, 0, 0, 0};
    if (g < 2) afA = *reinterpret_cast<const bf8_t*>(wsA + lr * 16 + g * 8);
    f4_t fz = {0.f, 0.f, 0.f, 0.f};
    f4_t fac = MFMA16(afA, xf, fz);

    // ---- epilogue ----
    f4_t xv = *reinterpret_cast<const f4_t*>(x + bb * 16 + g * 4);
    f4_t xg = *reinterpret_cast<const f4_t*>(x_goal + g * 4);
    f4_t k1b = *reinterpret_cast<const f4_t*>(K1b_b + g * 4);
    f4_t k2b = *reinterpret_cast<const f4_t*>(K2b_b + g * 4);
    f4_t bd0 = *reinterpret_cast<const f4_t*>(B_dyn + g * 8);
    f4_t bd1 = *reinterpret_cast<const f4_t*>(B_dyn + g * 8 + 4);
    float up0 = 0.f, up1 = 0.f, Lf = 0.f;
#pragma unroll
    for (int r = 0; r < 4; ++r) {
        float dx = xv[r] - xg[r];
        up0 = fmaf(k1[r] + k1b[r], dx, up0);
        up1 = fmaf(k2[r] + k2b[r], dx, up1);
        Lf = fmaf(gacc[r], fac[r], Lf);
    }
    float Lg0 = gacc[0] * bd0[0] + gacc[1] * bd0[2] + gacc[2] * bd1[0] + gacc[3] * bd1[2];
    float Lg1 = gacc[0] * bd0[1] + gacc[1] * bd0[3] + gacc[2] * bd1[1] + gacc[3] * bd1[3];
    up0 += __shfl_xor(up0, 16); up0 += __shfl_xor(up0, 32);
    up1 += __shfl_xor(up1, 16); up1 += __shfl_xor(up1, 32);
    Lf += __shfl_xor(Lf, 16); Lf += __shfl_xor(Lf, 32);
    Lg0 += __shfl_xor(Lg0, 16); Lg0 += __shfl_xor(Lg0, 32);
    Lg1 += __shfl_xor(Lg1, 16); Lg1 += __shfl_xor(Lg1, 32);
    vsum += __shfl_xor(vsum, 16); vsum += __shfl_xor(vsum, 32);

    float u0 = u_eq[0] - up0;
    float u1 = u_eq[1] - up1;
    float V = 0.5f * vsum;
    float G = fmaf(Lg0, u0, fmaf(Lg1, u1, V));
    float Vd = 0.5f * (fmaxf(Lf + G, 0.f) + fmaxf(fmaf(1.2f, Lf, G), 0.f));

    if (g == 0) {
        float2 uo; uo.x = u0; uo.y = u1;
        *reinterpret_cast<float2*>(out + 2 * bb) = uo;
    } else if (g == 1) {
        out[2 * B + 1 + bb] = V;
    } else if (g == 2) {
        out[3 * B + 1 + bb] = Vd;
    }
}

extern "C" void kernel_launch(void* const* d_in, const int* in_sizes, int n_in,
                              void* d_out, int out_size, void* d_ws, size_t ws_size,
                              hipStream_t stream) {
    const float* x = (const float*)d_in[0];
    const float* V1_w = (const float*)d_in[1];
    const float* V1_b = (const float*)d_in[2];
    const float* V2_w = (const float*)d_in[3];
    const float* V2_b = (const float*)d_in[4];
    const float* K1a_w = (const float*)d_in[5];
    const float* K1a_b = (const float*)d_in[6];
    const float* K1b_w = (const float*)d_in[7];
    const float* K1b_b = (const float*)d_in[8];
    const float* K2a_w = (const float*)d_in[9];
    const float* K2a_b = (const float*)d_in[10];
    const float* K2b_w = (const float*)d_in[11];
    const float* K2b_b = (const float*)d_in[12];
    const float* A_dyn = (const float*)d_in[13];
    const float* B_dyn = (const float*)d_in[14];
    const float* x_goal = (const float*)d_in[15];
    const float* u_eq = (const float*)d_in[16];
    float* out = (float*)d_out;
    unsigned short* ws = (unsigned short*)d_ws;

    const int B = in_sizes[0] / 16;   // 65536
    const size_t smem = 143360;       // 140 KB: V2s+V2Ts+V1T+K1b+K2b + 8x8K act
    (void)hipFuncSetAttribute(reinterpret_cast<const void*>(clf_mfma_kernel),
                              hipFuncAttributeMaxDynamicSharedMemorySize, (int)smem);
    prep_weights<<<64, 256, 0, stream>>>(V1_w, V2_w, K1a_w, K1b_w, K2a_w, K2b_w, A_dyn, ws);
    clf_mfma_kernel<<<512, 512, smem, stream>>>(
        x, V1_b, V2_b, K1a_b, K1b_b, K2a_b, K2b_b,
        B_dyn, x_goal, u_eq, ws, out, B);
}